// Round 11
// baseline (114.486 us; speedup 1.0000x reference)
//
#include <hip/hip_runtime.h>
#include <hip/hip_bf16.h>

#define DEV __device__ __forceinline__

typedef __attribute__((ext_vector_type(8))) short bf16x8;
typedef __attribute__((ext_vector_type(4))) float f32x4;

DEV float b2f(unsigned short u) {
    unsigned int v = ((unsigned int)u) << 16;
    float f; __builtin_memcpy(&f, &v, 4); return f;
}
DEV unsigned short f2b(float f) {            // RNE via bit-ops
    unsigned int v; __builtin_memcpy(&v, &f, 4);
    v = (v + 0x7fffu + ((v >> 16) & 1u)) >> 16;
    return (unsigned short)v;
}
DEV unsigned short f2b_hw(float f) {         // hardware cvt (RNE)
    __hip_bfloat16 h = __float2bfloat16(f);
    unsigned short u; __builtin_memcpy(&u, &h, 2); return u;
}

DEV f32x4 mfma16(bf16x8 a, bf16x8 b, f32x4 c) {
    return __builtin_amdgcn_mfma_f32_16x16x32_bf16(a, b, c, 0, 0, 0);
}

// global -> LDS async copy, 16B per lane; lds dest = uniform base + lane*16
DEV void stage16(const void* g, void* l) {
    __builtin_amdgcn_global_load_lds((const __attribute__((address_space(1))) void*)g,
                                     (__attribute__((address_space(3))) void*)l, 16, 0, 0);
}

#define WAIT_VM6()  asm volatile("s_waitcnt vmcnt(6)" ::: "memory")
#define WAIT_VM3()  asm volatile("s_waitcnt vmcnt(3)" ::: "memory")
#define WAIT_VM0()  asm volatile("s_waitcnt vmcnt(0)" ::: "memory")
#define WAIT_LGKM() asm volatile("s_waitcnt lgkmcnt(0)" ::: "memory")
#define BAR()       __builtin_amdgcn_s_barrier()
#define SCHED()     __builtin_amdgcn_sched_barrier(0)

constexpr float SCALE_L2E = 0.125f * 1.44269504088896340736f;  // DH^-0.5 * log2(e)

// ---------------------------------------------------------------------------
// K0a: elementwise fp32->bf16: xb[4096][512] = x ; wkt[64][64] = wk_ret copy.
// ---------------------------------------------------------------------------
__global__ void k_elem(const float* __restrict__ x,
                       const float* __restrict__ wk_ret,
                       unsigned short* __restrict__ xb,
                       unsigned short* __restrict__ wkt)
{
    const int T1 = 4096 * 512;
    const int T4 = 64 * 64;
    const int total = T1 + T4;
    for (int idx = blockIdx.x * blockDim.x + threadIdx.x; idx < total;
         idx += gridDim.x * blockDim.x) {
        if (idx < T1) xb[idx] = f2b(x[idx]);
        else          wkt[idx - T1] = f2b(wk_ret[idx - T1]);
    }
}

// ---------------------------------------------------------------------------
// K0b: LDS-tiled 32x32 transposes (coalesced read AND write):
//  wt[1664][512]: rows 0..511 = wq_s^T, 512..1023 = wk_s^T,
//                 1024..1151 = wv_r^T, 1152..1663 = wq_r^T
//  wot[512][512] = w_out^T
// grid 1088 blocks x 256 threads.
// ---------------------------------------------------------------------------
__global__ __launch_bounds__(256) void k_trans(const float* __restrict__ wq_s,
                                               const float* __restrict__ wk_s,
                                               const float* __restrict__ wv_r,
                                               const float* __restrict__ wq_r,
                                               const float* __restrict__ w_out,
                                               unsigned short* __restrict__ wt,
                                               unsigned short* __restrict__ wot)
{
    __shared__ float tl[32][33];
    int m = blockIdx.x;
    const float* src; unsigned short* dst;
    int base, srcld, kt, nt;
    if (m < 256)      { src = wq_s;  dst = wt;  base = 0;    srcld = 512; kt = m >> 4; nt = m & 15; }
    else if (m < 512) { m -= 256; src = wk_s;  dst = wt;  base = 512;  srcld = 512; kt = m >> 4; nt = m & 15; }
    else if (m < 576) { m -= 512; src = wv_r;  dst = wt;  base = 1024; srcld = 128; kt = m >> 2; nt = m & 3; }
    else if (m < 832) { m -= 576; src = wq_r;  dst = wt;  base = 1152; srcld = 512; kt = m >> 4; nt = m & 15; }
    else              { m -= 832; src = w_out; dst = wot; base = 0;    srcld = 512; kt = m >> 4; nt = m & 15; }

    const int r = threadIdx.x >> 5, c = threadIdx.x & 31;
#pragma unroll
    for (int s = 0; s < 4; ++s) {
        int rr = r + 8 * s;
        tl[rr][c] = src[(size_t)(kt * 32 + rr) * srcld + nt * 32 + c];
    }
    __syncthreads();
#pragma unroll
    for (int s = 0; s < 4; ++s) {
        int rr = r + 8 * s;
        dst[(size_t)(base + nt * 32 + rr) * 512 + kt * 32 + c] = f2b(tl[c][rr]);
    }
}

// ---------------------------------------------------------------------------
// K1/K3: staged GEMM  C[4096][N*] = A(bf16 [4096][512]) @ Bt(bf16 [N][512])^T
// BM=128, BN=64, BK=64; 4 waves 2x2, wave (wr,wc) owns 64x32 of C.
// Raw s_barrier + counted vmcnt (R10 structure, unchanged).
// EPI=0: scatter epilogue into qs/ks/rqb/vt.  EPI=1: fp32 store epilogue.
// ---------------------------------------------------------------------------
template<int EPI>
__global__ __launch_bounds__(256, 2) void k_gemm(const unsigned short* __restrict__ A,
                                                 const unsigned short* __restrict__ Bt,
                                                 unsigned short* __restrict__ qs,
                                                 unsigned short* __restrict__ ks,
                                                 unsigned short* __restrict__ rqb,
                                                 unsigned short* __restrict__ vt,
                                                 float* __restrict__ out)
{
    __shared__ unsigned char ab_lds[49152];

    const int tid = threadIdx.x;
    const int lane = tid & 63, wid = tid >> 6;
    const int lr = lane & 15, lg = lane >> 4;
    const int wr = wid >> 1, wc = wid & 1;
    const int brow0 = blockIdx.x * 128;
    const int bcol0 = blockIdx.y * 64;

    const int sub = lane >> 3;            // row within 8-row stripe
    const int chk = lane & 7;             // 16B chunk slot
    const int scs = chk ^ sub;            // swizzled source chunk

    const f32x4 z = {0.f, 0.f, 0.f, 0.f};
    f32x4 acc[4][2];
#pragma unroll
    for (int m = 0; m < 4; ++m)
#pragma unroll
        for (int n = 0; n < 2; ++n) acc[m][n] = z;

    const unsigned short* Ab = A + (size_t)brow0 * 512;

    auto STAGE = [&](int buf, int k0) {
        unsigned char* ab = ab_lds + buf * 16384;
        unsigned char* bb = ab_lds + 32768 + buf * 8192;
#pragma unroll
        for (int ii = 0; ii < 4; ++ii) {
            int r0 = wid * 32 + ii * 8;
            const unsigned short* g = Ab + (size_t)(r0 + sub) * 512 + k0 + scs * 8;
            stage16(g, ab + r0 * 128);
        }
#pragma unroll
        for (int ii = 0; ii < 2; ++ii) {
            int r0 = wid * 16 + ii * 8;
            const unsigned short* g = Bt + (size_t)(bcol0 + r0 + sub) * 512 + k0 + scs * 8;
            stage16(g, bb + r0 * 128);
        }
    };

    auto COMPUTE = [&](const int cur) {
        const unsigned char* ab = ab_lds + cur * 16384;
        const unsigned char* bb = ab_lds + 32768 + cur * 8192;
#pragma unroll
        for (int ksb = 0; ksb < 2; ++ksb) {
            const int c = ksb * 4 + lg;                       // k-chunk 0..7
            bf16x8 bfr[2];
#pragma unroll
            for (int n = 0; n < 2; ++n) {
                int row = wc * 32 + n * 16 + lr;
                bfr[n] = *(const bf16x8*)(bb + row * 128 + ((c ^ (row & 7)) << 4));
            }
#pragma unroll
            for (int m = 0; m < 4; ++m) {
                int row = wr * 64 + m * 16 + lr;
                bf16x8 af = *(const bf16x8*)(ab + row * 128 + ((c ^ (row & 7)) << 4));
                acc[m][0] = mfma16(af, bfr[0], acc[m][0]);
                acc[m][1] = mfma16(af, bfr[1], acc[m][1]);
            }
        }
    };

    STAGE(0, 0);
#pragma unroll 1
    for (int it = 0; it < 3; ++it) {
        STAGE(1, (2 * it + 1) * 64);
        WAIT_VM6(); BAR(); SCHED();
        COMPUTE(0);
        WAIT_LGKM(); SCHED(); BAR(); SCHED();
        STAGE(0, (2 * it + 2) * 64);
        WAIT_VM6(); BAR(); SCHED();
        COMPUTE(1);
        WAIT_LGKM(); SCHED(); BAR(); SCHED();
    }
    STAGE(1, 7 * 64);
    WAIT_VM6(); BAR(); SCHED();
    COMPUTE(0);
    WAIT_LGKM(); SCHED(); BAR(); SCHED();
    WAIT_VM0(); BAR(); SCHED();
    COMPUTE(1);

#pragma unroll
    for (int m = 0; m < 4; ++m) {
#pragma unroll
        for (int n = 0; n < 2; ++n) {
#pragma unroll
            for (int i = 0; i < 4; ++i) {
                int gr = brow0 + wr * 64 + m * 16 + lg * 4 + i;
                int gc = bcol0 + wc * 32 + n * 16 + lr;
                float v = acc[m][n][i];
                if (EPI == 1) {
                    out[(size_t)gr * 512 + gc] = v;
                } else {
                    int b = gr >> 11, in = gr & 2047;
                    if (gc < 512) {
                        int s = gc >> 6, d = gc & 63;
                        qs[((b * 8 + s) * 2048 + in) * 64 + d] = f2b(v * SCALE_L2E);
                    } else if (gc < 1024) {
                        int cgc = gc - 512; int s = cgc >> 6, d = cgc & 63;
                        ks[((b * 8 + s) * 2048 + in) * 64 + d] = f2b(v);
                    } else if (gc < 1152) {
                        int cgc = gc - 1024;             // 0..127 = r*64+d
                        vt[(b * 128 + cgc) * 2048 + in] = f2b(v);
                    } else {
                        int cgc = gc - 1152; int s = cgc >> 6, d = cgc & 63;
                        rqb[((b * 8 + s) * 2048 + in) * 64 + d] = f2b(v * SCALE_L2E);
                    }
                }
            }
        }
    }
}

// ---------------------------------------------------------------------------
// K2: flash attention + fused retrieval composition.
// R11: symmetric d-split x2. 512 blocks x 512 threads (8 waves):
//   wave w: q-sub (w&3) -> 16 q-rows; PV half h=(w>>2) -> r=h columns only.
// Each wave duplicates QK^T+softmax (cheap: MFMA 17% busy) but does half
// the PV -> total waves 4096 = 4/SIMD (2 blocks/CU x 16 waves).
// K/V staging shared by all 8 waves: 24 x 1KB stripes, 3 per wave (vmcnt(3)).
// LDS buf-major: buf b @ b*24576 { K 8KB | V 16KB }.
// Epilogue: each half computes own sim via T-MFMA; h=1 publishes sim1 +
// normalized retr1 into dead kv_lds buf0 region; h=0 combines, stores ob.
// ---------------------------------------------------------------------------
__global__ __launch_bounds__(512, 4) void k_attn(const unsigned short* __restrict__ qs,
                                                 const unsigned short* __restrict__ ks,
                                                 const unsigned short* __restrict__ rqb,
                                                 const unsigned short* __restrict__ vt,
                                                 const unsigned short* __restrict__ wkt,
                                                 unsigned short* __restrict__ ob)
{
    __shared__ unsigned char kv_lds[49152];           // 2 bufs x (K 8KB + V 16KB)
    __shared__ unsigned short p_lds[8][16][72];       // 18.4 KB

    const int tid = threadIdx.x;
    const int lane = tid & 63, wid = tid >> 6;        // wid 0..7
    const int lr = lane & 15, lg = lane >> 4;
    const int qsub = wid & 3, h = wid >> 2;
    const int bid = blockIdx.x;
    const int bs = bid >> 5, qt = bid & 31;           // bs = b*8+s
    const int gb = bs >> 3, gs = bs & 7;
    const int qrow0 = qt * 64 + qsub * 16;

    const int sub = lane >> 3;                        // row within 8-row stripe
    const int scs = (lane & 7) ^ sub;                 // swizzled source chunk
    const int swz = lr & 7;                           // read-side XOR

    // Q fragments, kept in registers for the whole main loop
    const unsigned short* qbase = qs + ((size_t)bs * 2048 + qrow0 + lr) * 64 + lg * 8;
    const bf16x8 q0 = *(const bf16x8*)(qbase);
    const bf16x8 q1 = *(const bf16x8*)(qbase + 32);

    const unsigned short* kbase = ks + (size_t)bs * 131072;     // [2048][64]
    const unsigned short* vbase = vt + (size_t)gb * 262144;     // [128][2048]

    const f32x4 z = {0.f, 0.f, 0.f, 0.f};
    bf16x8 ones;
#pragma unroll
    for (int j = 0; j < 8; ++j) ones[j] = (short)0x3F80;

    float m_r[4];
    f32x4 acc[4];                                     // own half's PV (r = h)
    f32x4 acc_l = z;
#pragma unroll
    for (int i = 0; i < 4; ++i) m_r[i] = -3.0e38f;
#pragma unroll
    for (int cc = 0; cc < 4; ++cc) acc[cc] = z;

    // --- stage stripes: 24 x 1KB per tile {K: s<8 row s*8; V: s>=8 d-row (s-8)*8}
    // wave stages stripes 3w..3w+2; incremental per-lane source pointers.
    const unsigned short* sp[3];
    int step[3], loff[3];
#pragma unroll
    for (int j = 0; j < 3; ++j) {
        int s = wid * 3 + j;
        if (s < 8) { sp[j] = kbase + (size_t)(s * 8 + sub) * 64 + scs * 8;          step[j] = 4096; }
        else       { sp[j] = vbase + (size_t)((s - 8) * 8 + sub) * 2048 + scs * 8;  step[j] = 64;   }
        loff[j] = s * 1024;
    }

    auto STAGE = [&](const int buf) {
        unsigned char* base = kv_lds + buf * 24576;
#pragma unroll
        for (int j = 0; j < 3; ++j) {
            stage16(sp[j], base + loff[j]);
            sp[j] += step[j];
        }
    };

    auto COMPUTE = [&](const int cur) {
        const unsigned char* kb = kv_lds + cur * 24576;
        const unsigned char* vb = kb + 8192;

        // --- S = Q K^T (16 x 64 tile) from LDS (swizzled reads)
        f32x4 s[4];
        __builtin_amdgcn_s_setprio(1);
#pragma unroll
        for (int ct = 0; ct < 4; ++ct) {
            const unsigned char* kr = kb + (ct * 16 + lr) * 128;
            bf16x8 kf0 = *(const bf16x8*)(kr + ((lg ^ swz) << 4));
            bf16x8 kf1 = *(const bf16x8*)(kr + (((lg + 4) ^ swz) << 4));
            f32x4 t = z;
            t = mfma16(q0, kf0, t);
            t = mfma16(q1, kf1, t);
            s[ct] = t;
        }
        __builtin_amdgcn_s_setprio(0);

        // --- deferred-max online softmax (log2 units)
        float lm[4];
        bool need = false;
#pragma unroll
        for (int i = 0; i < 4; ++i) {
            lm[i] = fmaxf(fmaxf(s[0][i], s[1][i]), fmaxf(s[2][i], s[3][i]));
            need = need || (lm[i] > m_r[i] + 8.0f);
        }
        if (__any(need)) {
#pragma unroll
            for (int i = 0; i < 4; ++i) {
                float mx = lm[i];
                mx = fmaxf(mx, __shfl_xor(mx, 1, 16));
                mx = fmaxf(mx, __shfl_xor(mx, 2, 16));
                mx = fmaxf(mx, __shfl_xor(mx, 4, 16));
                mx = fmaxf(mx, __shfl_xor(mx, 8, 16));
                float m_new = fmaxf(m_r[i], mx);
                float alpha = exp2f(m_r[i] - m_new);
#pragma unroll
                for (int cc = 0; cc < 4; ++cc) acc[cc][i] *= alpha;
                acc_l[i] *= alpha;
                m_r[i] = m_new;
            }
        }
        // --- P = exp2(S - m), bf16, through wave-private LDS tile
#pragma unroll
        for (int i = 0; i < 4; ++i) {
#pragma unroll
            for (int ct = 0; ct < 4; ++ct)
                p_lds[wid][lg * 4 + i][ct * 16 + lr] = f2b_hw(exp2f(s[ct][i] - m_r[i]));
        }
        bf16x8 pf0 = *(const bf16x8*)(&p_lds[wid][lr][lg * 8]);
        bf16x8 pf1 = *(const bf16x8*)(&p_lds[wid][lr][32 + lg * 8]);

        // --- PV: own half only (c8 = h*4 + cc) (+ row-sum via ones-column)
        __builtin_amdgcn_s_setprio(1);
#pragma unroll
        for (int cc = 0; cc < 4; ++cc) {
            const unsigned char* vr = vb + ((h * 4 + cc) * 16 + lr) * 128;
            bf16x8 vf0 = *(const bf16x8*)(vr + ((lg ^ swz) << 4));
            bf16x8 vf1 = *(const bf16x8*)(vr + (((lg + 4) ^ swz) << 4));
            acc[cc] = mfma16(pf0, vf0, acc[cc]);
            acc[cc] = mfma16(pf1, vf1, acc[cc]);
        }
        acc_l = mfma16(pf0, ones, acc_l);
        acc_l = mfma16(pf1, ones, acc_l);
        __builtin_amdgcn_s_setprio(0);
    };

    STAGE(0);                                         // tile 0 -> buf0

#pragma unroll 1
    for (int it = 0; it < 15; ++it) {
        STAGE(1);                                     // tile 2it+1
        WAIT_VM3(); BAR(); SCHED();
        COMPUTE(0);                                   // tile 2it
        WAIT_LGKM(); SCHED(); BAR(); SCHED();
        STAGE(0);                                     // tile 2it+2
        WAIT_VM3(); BAR(); SCHED();
        COMPUTE(1);                                   // tile 2it+1
        WAIT_LGKM(); SCHED(); BAR(); SCHED();
    }
    STAGE(1);                                         // tile 31
    WAIT_VM3(); BAR(); SCHED();
    COMPUTE(0);                                       // tile 30
    WAIT_LGKM(); SCHED(); BAR(); SCHED();
    WAIT_VM0(); BAR(); SCHED();
    COMPUTE(1);                                       // tile 31 (reads buf1 only)

    // --- epilogue. retr[r=h][d=cc*16+lr] rows lg*4+i, weight inv = 1/l.
    float inv[4];
#pragma unroll
    for (int i = 0; i < 4; ++i) inv[i] = 1.0f / acc_l[i];

    // rq fragments (pre-scaled by DH^-0.5*log2e in k_gemm<0>)
    const unsigned short* rqbase = rqb + ((size_t)bs * 2048 + qrow0 + lr) * 64 + lg * 8;
    const bf16x8 rq0 = *(const bf16x8*)(rqbase);
    const bf16x8 rq1 = *(const bf16x8*)(rqbase + 32);

    // T[q][d] = sum_dp rq[q][dp] * wk_ret[d][dp]  (both halves compute)
    f32x4 Tt[4];
#pragma unroll
    for (int ct = 0; ct < 4; ++ct) {
        bf16x8 wb0 = *(const bf16x8*)(wkt + (ct * 16 + lr) * 64 + lg * 8);
        bf16x8 wb1 = *(const bf16x8*)(wkt + (ct * 16 + lr) * 64 + 32 + lg * 8);
        f32x4 t = z;
        t = mfma16(rq0, wb0, t);
        t = mfma16(rq1, wb1, t);
        Tt[ct] = t;
    }

    // own sim_h[row] = sum_d T[row][d] * retr_h_norm[row][d]   (log2 units)
    float simh[4];
#pragma unroll
    for (int i = 0; i < 4; ++i) {
        float sh = 0.f;
#pragma unroll
        for (int cc = 0; cc < 4; ++cc) sh += Tt[cc][i] * acc[cc][i];
        sh *= inv[i];
        sh += __shfl_xor(sh, 1, 16);
        sh += __shfl_xor(sh, 2, 16);
        sh += __shfl_xor(sh, 4, 16);
        sh += __shfl_xor(sh, 8, 16);
        simh[i] = sh;
    }

    // exchange through dead kv_lds buf0 region (last tile used buf1 only):
    //  xch[4][16][68] f32 (17408 B) + simx[4][16] f32 @ +17408
    float* xch  = (float*)kv_lds;
    float* simx = (float*)(kv_lds + 17408);
    if (h == 1) {
#pragma unroll
        for (int cc = 0; cc < 4; ++cc)
#pragma unroll
            for (int i = 0; i < 4; ++i)
                xch[(qsub * 16 + lg * 4 + i) * 68 + cc * 16 + lr] = acc[cc][i] * inv[i];
        if (lr == 0) {
#pragma unroll
            for (int i = 0; i < 4; ++i) simx[qsub * 16 + lg * 4 + i] = simh[i];
        }
    }
    BAR();
    if (h == 1) return;

    // h==0: combine r=0 (own) with r=1 (LDS) and store ob
#pragma unroll
    for (int i = 0; i < 4; ++i) {
        float s1 = simx[qsub * 16 + lg * 4 + i];
        float mm = fmaxf(simh[i], s1);
        float e0 = exp2f(simh[i] - mm), e1 = exp2f(s1 - mm);
        float inw = 1.0f / (e0 + e1);
        float w0 = e0 * inw, w1 = e1 * inw;
#pragma unroll
        for (int cc = 0; cc < 4; ++cc) {
            float o = w0 * acc[cc][i] * inv[i]
                    + w1 * xch[(qsub * 16 + lg * 4 + i) * 68 + cc * 16 + lr];
            ob[((size_t)gb * 2048 + qrow0 + lg * 4 + i) * 512 + gs * 64 + cc * 16 + lr] = f2b_hw(o);
        }
    }
}

// ---------------------------------------------------------------------------
extern "C" void kernel_launch(void* const* d_in, const int* in_sizes, int n_in,
                              void* d_out, int out_size, void* d_ws, size_t ws_size,
                              hipStream_t stream)
{
    (void)in_sizes; (void)n_in; (void)out_size; (void)ws_size;
    const float* x      = (const float*)d_in[0];
    const float* wq_s   = (const float*)d_in[1];
    const float* wk_s   = (const float*)d_in[2];
    const float* wv_r   = (const float*)d_in[3];
    const float* wq_r   = (const float*)d_in[4];
    const float* wk_ret = (const float*)d_in[5];
    const float* w_out  = (const float*)d_in[6];

    char* ws = (char*)d_ws;                            // needs ~24.3 MB
    unsigned short* xb  = (unsigned short*)(ws + 0);          // [4096][512]
    unsigned short* wt  = (unsigned short*)(ws + 4194304);    // [1664][512]
    unsigned short* qsb = (unsigned short*)(ws + 5898240);    // [2][8][2048][64]
    unsigned short* ksb = (unsigned short*)(ws + 10092544);   // [2][8][2048][64]
    unsigned short* rqb = (unsigned short*)(ws + 14286848);   // [2][8][2048][64]
    unsigned short* vtb = (unsigned short*)(ws + 18481152);   // [2][128][2048]
    unsigned short* obb = (unsigned short*)(ws + 19529728);   // [2][2048][512]
    unsigned short* wot = (unsigned short*)(ws + 23724032);   // [512][512]
    unsigned short* wkt = (unsigned short*)(ws + 24248320);   // [64][64]

    hipLaunchKernelGGL(k_elem, dim3(1024), dim3(256), 0, stream,
                       x, wk_ret, xb, wkt);
    hipLaunchKernelGGL(k_trans, dim3(1088), dim3(256), 0, stream,
                       wq_s, wk_s, wv_r, wq_r, w_out, wt, wot);
    hipLaunchKernelGGL((k_gemm<0>), dim3(32, 26), dim3(256), 0, stream,
                       xb, wt, qsb, ksb, rqb, vtb, (float*)nullptr);
    hipLaunchKernelGGL(k_attn, dim3(512), dim3(512), 0, stream,
                       qsb, ksb, rqb, vtb, wkt, obb);
    hipLaunchKernelGGL((k_gemm<1>), dim3(32, 8), dim3(256), 0, stream,
                       obb, wot, (unsigned short*)nullptr, (unsigned short*)nullptr,
                       (unsigned short*)nullptr, (unsigned short*)nullptr, (float*)d_out);
}

// Round 12
// 91.970 us; speedup vs baseline: 1.2448x; 1.2448x over previous
//
#include <hip/hip_runtime.h>
#include <hip/hip_bf16.h>

#define DEV __device__ __forceinline__

typedef __attribute__((ext_vector_type(8))) short bf16x8;
typedef __attribute__((ext_vector_type(4))) float f32x4;

DEV float b2f(unsigned short u) {
    unsigned int v = ((unsigned int)u) << 16;
    float f; __builtin_memcpy(&f, &v, 4); return f;
}
DEV unsigned short f2b(float f) {            // RNE via bit-ops
    unsigned int v; __builtin_memcpy(&v, &f, 4);
    v = (v + 0x7fffu + ((v >> 16) & 1u)) >> 16;
    return (unsigned short)v;
}
DEV unsigned short f2b_hw(float f) {         // hardware cvt (RNE)
    __hip_bfloat16 h = __float2bfloat16(f);
    unsigned short u; __builtin_memcpy(&u, &h, 2); return u;
}

DEV f32x4 mfma16(bf16x8 a, bf16x8 b, f32x4 c) {
    return __builtin_amdgcn_mfma_f32_16x16x32_bf16(a, b, c, 0, 0, 0);
}

// global -> LDS async copy, 16B per lane; lds dest = uniform base + lane*16
DEV void stage16(const void* g, void* l) {
    __builtin_amdgcn_global_load_lds((const __attribute__((address_space(1))) void*)g,
                                     (__attribute__((address_space(3))) void*)l, 16, 0, 0);
}

#define WAIT_VM6()  asm volatile("s_waitcnt vmcnt(6)" ::: "memory")
#define WAIT_VM3()  asm volatile("s_waitcnt vmcnt(3)" ::: "memory")
#define WAIT_VM0()  asm volatile("s_waitcnt vmcnt(0)" ::: "memory")
#define WAIT_LGKM() asm volatile("s_waitcnt lgkmcnt(0)" ::: "memory")
#define BAR()       __builtin_amdgcn_s_barrier()
#define SCHED()     __builtin_amdgcn_sched_barrier(0)

constexpr float SCALE_L2E = 0.125f * 1.44269504088896340736f;  // DH^-0.5 * log2(e)

// ---------------------------------------------------------------------------
// K0a: elementwise fp32->bf16: xb[4096][512] = x ; wkt[64][64] = wk_ret copy.
// ---------------------------------------------------------------------------
__global__ void k_elem(const float* __restrict__ x,
                       const float* __restrict__ wk_ret,
                       unsigned short* __restrict__ xb,
                       unsigned short* __restrict__ wkt)
{
    const int T1 = 4096 * 512;
    const int T4 = 64 * 64;
    const int total = T1 + T4;
    for (int idx = blockIdx.x * blockDim.x + threadIdx.x; idx < total;
         idx += gridDim.x * blockDim.x) {
        if (idx < T1) xb[idx] = f2b(x[idx]);
        else          wkt[idx - T1] = f2b(wk_ret[idx - T1]);
    }
}

// ---------------------------------------------------------------------------
// K0b: LDS-tiled 32x32 transposes (coalesced read AND write):
//  wt[1664][512]: rows 0..511 = wq_s^T, 512..1023 = wk_s^T,
//                 1024..1151 = wv_r^T, 1152..1663 = wq_r^T
//  wot[512][512] = w_out^T
// ---------------------------------------------------------------------------
__global__ __launch_bounds__(256) void k_trans(const float* __restrict__ wq_s,
                                               const float* __restrict__ wk_s,
                                               const float* __restrict__ wv_r,
                                               const float* __restrict__ wq_r,
                                               const float* __restrict__ w_out,
                                               unsigned short* __restrict__ wt,
                                               unsigned short* __restrict__ wot)
{
    __shared__ float tl[32][33];
    int m = blockIdx.x;
    const float* src; unsigned short* dst;
    int base, srcld, kt, nt;
    if (m < 256)      { src = wq_s;  dst = wt;  base = 0;    srcld = 512; kt = m >> 4; nt = m & 15; }
    else if (m < 512) { m -= 256; src = wk_s;  dst = wt;  base = 512;  srcld = 512; kt = m >> 4; nt = m & 15; }
    else if (m < 576) { m -= 512; src = wv_r;  dst = wt;  base = 1024; srcld = 128; kt = m >> 2; nt = m & 3; }
    else if (m < 832) { m -= 576; src = wq_r;  dst = wt;  base = 1152; srcld = 512; kt = m >> 4; nt = m & 15; }
    else              { m -= 832; src = w_out; dst = wot; base = 0;    srcld = 512; kt = m >> 4; nt = m & 15; }

    const int r = threadIdx.x >> 5, c = threadIdx.x & 31;
#pragma unroll
    for (int s = 0; s < 4; ++s) {
        int rr = r + 8 * s;
        tl[rr][c] = src[(size_t)(kt * 32 + rr) * srcld + nt * 32 + c];
    }
    __syncthreads();
#pragma unroll
    for (int s = 0; s < 4; ++s) {
        int rr = r + 8 * s;
        dst[(size_t)(base + nt * 32 + rr) * 512 + kt * 32 + c] = f2b(tl[c][rr]);
    }
}

// ---------------------------------------------------------------------------
// K1/K3: staged GEMM  C[4096][N*] = A(bf16 [4096][512]) @ Bt(bf16 [N][512])^T
// BM=128, BN=64, BK=64; 4 waves 2x2, wave (wr,wc) owns 64x32 of C.
// Raw s_barrier + counted vmcnt (R10 structure, unchanged).
// EPI=0: scatter epilogue into qs/ks/rqb/vt.  EPI=1: fp32 store epilogue.
// ---------------------------------------------------------------------------
template<int EPI>
__global__ __launch_bounds__(256, 2) void k_gemm(const unsigned short* __restrict__ A,
                                                 const unsigned short* __restrict__ Bt,
                                                 unsigned short* __restrict__ qs,
                                                 unsigned short* __restrict__ ks,
                                                 unsigned short* __restrict__ rqb,
                                                 unsigned short* __restrict__ vt,
                                                 float* __restrict__ out)
{
    __shared__ unsigned char ab_lds[49152];

    const int tid = threadIdx.x;
    const int lane = tid & 63, wid = tid >> 6;
    const int lr = lane & 15, lg = lane >> 4;
    const int wr = wid >> 1, wc = wid & 1;
    const int brow0 = blockIdx.x * 128;
    const int bcol0 = blockIdx.y * 64;

    const int sub = lane >> 3;            // row within 8-row stripe
    const int chk = lane & 7;             // 16B chunk slot
    const int scs = chk ^ sub;            // swizzled source chunk

    const f32x4 z = {0.f, 0.f, 0.f, 0.f};
    f32x4 acc[4][2];
#pragma unroll
    for (int m = 0; m < 4; ++m)
#pragma unroll
        for (int n = 0; n < 2; ++n) acc[m][n] = z;

    const unsigned short* Ab = A + (size_t)brow0 * 512;

    auto STAGE = [&](int buf, int k0) {
        unsigned char* ab = ab_lds + buf * 16384;
        unsigned char* bb = ab_lds + 32768 + buf * 8192;
#pragma unroll
        for (int ii = 0; ii < 4; ++ii) {
            int r0 = wid * 32 + ii * 8;
            const unsigned short* g = Ab + (size_t)(r0 + sub) * 512 + k0 + scs * 8;
            stage16(g, ab + r0 * 128);
        }
#pragma unroll
        for (int ii = 0; ii < 2; ++ii) {
            int r0 = wid * 16 + ii * 8;
            const unsigned short* g = Bt + (size_t)(bcol0 + r0 + sub) * 512 + k0 + scs * 8;
            stage16(g, bb + r0 * 128);
        }
    };

    auto COMPUTE = [&](const int cur) {
        const unsigned char* ab = ab_lds + cur * 16384;
        const unsigned char* bb = ab_lds + 32768 + cur * 8192;
#pragma unroll
        for (int ksb = 0; ksb < 2; ++ksb) {
            const int c = ksb * 4 + lg;                       // k-chunk 0..7
            bf16x8 bfr[2];
#pragma unroll
            for (int n = 0; n < 2; ++n) {
                int row = wc * 32 + n * 16 + lr;
                bfr[n] = *(const bf16x8*)(bb + row * 128 + ((c ^ (row & 7)) << 4));
            }
#pragma unroll
            for (int m = 0; m < 4; ++m) {
                int row = wr * 64 + m * 16 + lr;
                bf16x8 af = *(const bf16x8*)(ab + row * 128 + ((c ^ (row & 7)) << 4));
                acc[m][0] = mfma16(af, bfr[0], acc[m][0]);
                acc[m][1] = mfma16(af, bfr[1], acc[m][1]);
            }
        }
    };

    STAGE(0, 0);
#pragma unroll 1
    for (int it = 0; it < 3; ++it) {
        STAGE(1, (2 * it + 1) * 64);
        WAIT_VM6(); BAR(); SCHED();
        COMPUTE(0);
        WAIT_LGKM(); SCHED(); BAR(); SCHED();
        STAGE(0, (2 * it + 2) * 64);
        WAIT_VM6(); BAR(); SCHED();
        COMPUTE(1);
        WAIT_LGKM(); SCHED(); BAR(); SCHED();
    }
    STAGE(1, 7 * 64);
    WAIT_VM6(); BAR(); SCHED();
    COMPUTE(0);
    WAIT_LGKM(); SCHED(); BAR(); SCHED();
    WAIT_VM0(); BAR(); SCHED();
    COMPUTE(1);

#pragma unroll
    for (int m = 0; m < 4; ++m) {
#pragma unroll
        for (int n = 0; n < 2; ++n) {
#pragma unroll
            for (int i = 0; i < 4; ++i) {
                int gr = brow0 + wr * 64 + m * 16 + lg * 4 + i;
                int gc = bcol0 + wc * 32 + n * 16 + lr;
                float v = acc[m][n][i];
                if (EPI == 1) {
                    out[(size_t)gr * 512 + gc] = v;
                } else {
                    int b = gr >> 11, in = gr & 2047;
                    if (gc < 512) {
                        int s = gc >> 6, d = gc & 63;
                        qs[((b * 8 + s) * 2048 + in) * 64 + d] = f2b(v * SCALE_L2E);
                    } else if (gc < 1024) {
                        int cgc = gc - 512; int s = cgc >> 6, d = cgc & 63;
                        ks[((b * 8 + s) * 2048 + in) * 64 + d] = f2b(v);
                    } else if (gc < 1152) {
                        int cgc = gc - 1024;             // 0..127 = r*64+d
                        vt[(b * 128 + cgc) * 2048 + in] = f2b(v);
                    } else {
                        int cgc = gc - 1152; int s = cgc >> 6, d = cgc & 63;
                        rqb[((b * 8 + s) * 2048 + in) * 64 + d] = f2b(v * SCALE_L2E);
                    }
                }
            }
        }
    }
}

// ---------------------------------------------------------------------------
// K2: flash attention + fused retrieval composition.
// R12: key-split within staged tile (NO work duplication, unlike R11).
// 512 blocks x 512 threads (8 waves): wave w = q-sub (w&3, 16 rows) x
// key-half h=(w>>2). Both halves share each staged 64-key tile; h processes
// keys h*32..h*32+32 of it (own QK, own softmax m/l, own PV over all 128 d).
// Total waves 4096 = 4/SIMD at 2 blocks/CU. At the end: R3's in-LDS merge
// (h1 publishes raw acc+m+l into dead kv_lds region), h0 merges + runs the
// stage-2 epilogue (T-MFMA, r-softmax, combine) and stores ob.
// ---------------------------------------------------------------------------
__global__ __launch_bounds__(512, 4) void k_attn(const unsigned short* __restrict__ qs,
                                                 const unsigned short* __restrict__ ks,
                                                 const unsigned short* __restrict__ rqb,
                                                 const unsigned short* __restrict__ vt,
                                                 const unsigned short* __restrict__ wkt,
                                                 unsigned short* __restrict__ ob)
{
    // 2 bufs x (K 8KB @ +0 | V 16KB @ +8192) = 48KB; merge region aliases
    // this after the main loop (all kv reads done + barrier).
    __shared__ unsigned char kv_lds[49152];
    __shared__ unsigned short p_lds[8][16][40];       // 10.2 KB (pad 32->40)

    const int tid = threadIdx.x;
    const int lane = tid & 63, wid = tid >> 6;        // wid 0..7
    const int lr = lane & 15, lg = lane >> 4;
    const int qsub = wid & 3, h = wid >> 2;
    const int bid = blockIdx.x;
    const int bs = bid >> 5, qt = bid & 31;           // bs = b*8+s
    const int gb = bs >> 3, gs = bs & 7;
    const int qrow0 = qt * 64 + qsub * 16;

    const int sub = lane >> 3;                        // row within 8-row stripe
    const int scs = (lane & 7) ^ sub;                 // swizzled source chunk
    const int swz = lr & 7;                           // read-side XOR

    // Q fragments, kept in registers for the whole main loop
    const unsigned short* qbase = qs + ((size_t)bs * 2048 + qrow0 + lr) * 64 + lg * 8;
    const bf16x8 q0 = *(const bf16x8*)(qbase);
    const bf16x8 q1 = *(const bf16x8*)(qbase + 32);

    const unsigned short* kbase = ks + (size_t)bs * 131072;     // [2048][64]
    const unsigned short* vbase = vt + (size_t)gb * 262144;     // [128][2048]

    const f32x4 z = {0.f, 0.f, 0.f, 0.f};
    bf16x8 ones;
#pragma unroll
    for (int j = 0; j < 8; ++j) ones[j] = (short)0x3F80;

    float m_r[4];
    f32x4 acc[8];                                     // 16 rows x 128 d (own keys)
    f32x4 acc_l = z;
#pragma unroll
    for (int i = 0; i < 4; ++i) m_r[i] = -3.0e38f;
#pragma unroll
    for (int c8 = 0; c8 < 8; ++c8) acc[c8] = z;

    // --- stage stripes: 24 x 1KB per tile {s<8: K rows s*8; s>=8: V d-rows
    // (s-8)*8}; wave stages stripes 3w..3w+2 (incremental per-lane pointers).
    const unsigned short* sp[3];
    int step[3], loff[3];
#pragma unroll
    for (int j = 0; j < 3; ++j) {
        int s = wid * 3 + j;
        if (s < 8) { sp[j] = kbase + (size_t)(s * 8 + sub) * 64 + scs * 8;          step[j] = 4096; }
        else       { sp[j] = vbase + (size_t)((s - 8) * 8 + sub) * 2048 + scs * 8;  step[j] = 64;   }
        loff[j] = s * 1024;
    }

    auto STAGE = [&](const int buf) {
        unsigned char* base = kv_lds + buf * 24576;
#pragma unroll
        for (int j = 0; j < 3; ++j) {
            stage16(sp[j], base + loff[j]);
            sp[j] += step[j];
        }
    };

    auto COMPUTE = [&](const int cur) {
        const unsigned char* kb = kv_lds + cur * 24576;
        const unsigned char* vb = kb + 8192;

        // --- S = Q K^T: own 32 keys (rows h*32+ct*16+lr of K tile)
        f32x4 s[2];
        __builtin_amdgcn_s_setprio(1);
#pragma unroll
        for (int ct = 0; ct < 2; ++ct) {
            const unsigned char* kr = kb + (h * 32 + ct * 16 + lr) * 128;
            bf16x8 kf0 = *(const bf16x8*)(kr + ((lg ^ swz) << 4));
            bf16x8 kf1 = *(const bf16x8*)(kr + (((lg + 4) ^ swz) << 4));
            f32x4 t = z;
            t = mfma16(q0, kf0, t);
            t = mfma16(q1, kf1, t);
            s[ct] = t;
        }
        __builtin_amdgcn_s_setprio(0);

        // --- deferred-max online softmax (log2 units) over own 32 keys
        float lm[4];
        bool need = false;
#pragma unroll
        for (int i = 0; i < 4; ++i) {
            lm[i] = fmaxf(s[0][i], s[1][i]);
            need = need || (lm[i] > m_r[i] + 8.0f);
        }
        if (__any(need)) {
#pragma unroll
            for (int i = 0; i < 4; ++i) {
                float mx = lm[i];
                mx = fmaxf(mx, __shfl_xor(mx, 1, 16));
                mx = fmaxf(mx, __shfl_xor(mx, 2, 16));
                mx = fmaxf(mx, __shfl_xor(mx, 4, 16));
                mx = fmaxf(mx, __shfl_xor(mx, 8, 16));
                float m_new = fmaxf(m_r[i], mx);
                float alpha = exp2f(m_r[i] - m_new);
#pragma unroll
                for (int c8 = 0; c8 < 8; ++c8) acc[c8][i] *= alpha;
                acc_l[i] *= alpha;
                m_r[i] = m_new;
            }
        }
        // --- P = exp2(S - m), bf16, wave-private LDS tile [16][40]
#pragma unroll
        for (int i = 0; i < 4; ++i) {
#pragma unroll
            for (int ct = 0; ct < 2; ++ct)
                p_lds[wid][lg * 4 + i][ct * 16 + lr] = f2b_hw(exp2f(s[ct][i] - m_r[i]));
        }
        bf16x8 pf = *(const bf16x8*)(&p_lds[wid][lr][lg * 8]);

        // --- PV: own key-half's columns of V (key chunk base h*4+lg)
        __builtin_amdgcn_s_setprio(1);
#pragma unroll
        for (int c8 = 0; c8 < 8; ++c8) {
            const unsigned char* vr = vb + (c8 * 16 + lr) * 128;
            bf16x8 vf = *(const bf16x8*)(vr + (((h * 4 + lg) ^ swz) << 4));
            acc[c8] = mfma16(pf, vf, acc[c8]);
        }
        acc_l = mfma16(pf, ones, acc_l);
        __builtin_amdgcn_s_setprio(0);
    };

    STAGE(0);                                         // tile 0 -> buf0

#pragma unroll 1
    for (int it = 0; it < 15; ++it) {
        STAGE(1);                                     // tile 2it+1
        WAIT_VM3(); BAR(); SCHED();
        COMPUTE(0);                                   // tile 2it
        WAIT_LGKM(); SCHED(); BAR(); SCHED();
        STAGE(0);                                     // tile 2it+2
        WAIT_VM3(); BAR(); SCHED();
        COMPUTE(1);                                   // tile 2it+1
        WAIT_LGKM(); SCHED(); BAR(); SCHED();
    }
    STAGE(1);                                         // tile 31
    WAIT_VM3(); BAR(); SCHED();
    COMPUTE(0);                                       // tile 30
    WAIT_LGKM(); SCHED(); BAR(); SCHED();
    WAIT_VM0(); BAR(); SCHED();
    COMPUTE(1);                                       // tile 31

    // --- merge halves through LDS (aliases dead kv region; __syncthreads
    // drains all outstanding kv reads before h1 overwrites it)
    __syncthreads();
    float* mrg = (float*)kv_lds;                      // [4][16][132] = 33792 B
    float* ml  = (float*)(kv_lds + 33792);            // [4][16][2]   = 512 B
    if (h == 1) {
#pragma unroll
        for (int c8 = 0; c8 < 8; ++c8)
#pragma unroll
            for (int i = 0; i < 4; ++i)
                mrg[(qsub * 16 + lg * 4 + i) * 132 + c8 * 16 + lr] = acc[c8][i];
        if (lr == 0) {
#pragma unroll
            for (int i = 0; i < 4; ++i) {
                ml[(qsub * 16 + lg * 4 + i) * 2 + 0] = m_r[i];
                ml[(qsub * 16 + lg * 4 + i) * 2 + 1] = acc_l[i];
            }
        }
    }
    __syncthreads();
    if (h == 1) return;

    // h==0: flash-merge partner partials
    float inv[4];
    f32x4 accM[8];
#pragma unroll
    for (int i = 0; i < 4; ++i) {
        float m_b = ml[(qsub * 16 + lg * 4 + i) * 2 + 0];
        float l_b = ml[(qsub * 16 + lg * 4 + i) * 2 + 1];
        float m_new = fmaxf(m_r[i], m_b);
        float fa = exp2f(m_r[i] - m_new);
        float fb = exp2f(m_b - m_new);
        inv[i] = 1.0f / (acc_l[i] * fa + l_b * fb);
#pragma unroll
        for (int c8 = 0; c8 < 8; ++c8)
            accM[c8][i] = acc[c8][i] * fa + mrg[(qsub * 16 + lg * 4 + i) * 132 + c8 * 16 + lr] * fb;
    }

    // rq fragments (pre-scaled by DH^-0.5*log2e in k_gemm<0>)
    const unsigned short* rqbase = rqb + ((size_t)bs * 2048 + qrow0 + lr) * 64 + lg * 8;
    const bf16x8 rq0 = *(const bf16x8*)(rqbase);
    const bf16x8 rq1 = *(const bf16x8*)(rqbase + 32);

    // stage 2 via MFMA: T[q][d] = sum_dp rq[q][dp] * wk_ret[d][dp]
    f32x4 Tt[4];
#pragma unroll
    for (int ct = 0; ct < 4; ++ct) {
        bf16x8 wb0 = *(const bf16x8*)(wkt + (ct * 16 + lr) * 64 + lg * 8);
        bf16x8 wb1 = *(const bf16x8*)(wkt + (ct * 16 + lr) * 64 + 32 + lg * 8);
        f32x4 t = z;
        t = mfma16(rq0, wb0, t);
        t = mfma16(rq1, wb1, t);
        Tt[ct] = t;
    }

    // sim_r[row] = sum_{d} T[row][d] * retrN[row][r*64+d]   (log2 units)
    float w0v[4], w1v[4];
#pragma unroll
    for (int i = 0; i < 4; ++i) {
        float s0 = 0.f, s1 = 0.f;
#pragma unroll
        for (int ct = 0; ct < 4; ++ct) {
            s0 += Tt[ct][i] * accM[ct][i];
            s1 += Tt[ct][i] * accM[4 + ct][i];
        }
        s0 *= inv[i]; s1 *= inv[i];
        s0 += __shfl_xor(s0, 1, 16); s1 += __shfl_xor(s1, 1, 16);
        s0 += __shfl_xor(s0, 2, 16); s1 += __shfl_xor(s1, 2, 16);
        s0 += __shfl_xor(s0, 4, 16); s1 += __shfl_xor(s1, 4, 16);
        s0 += __shfl_xor(s0, 8, 16); s1 += __shfl_xor(s1, 8, 16);
        float mm = fmaxf(s0, s1);
        float e0 = exp2f(s0 - mm), e1 = exp2f(s1 - mm);
        float inw = 1.0f / (e0 + e1);
        w0v[i] = e0 * inw; w1v[i] = e1 * inw;
    }

    // --- combine r=2 and store ob[b][n][gs*64 + d]
#pragma unroll
    for (int ct = 0; ct < 4; ++ct) {
#pragma unroll
        for (int i = 0; i < 4; ++i) {
            float o = (w0v[i] * accM[ct][i] + w1v[i] * accM[4 + ct][i]) * inv[i];
            ob[((size_t)gb * 2048 + qrow0 + lg * 4 + i) * 512 + gs * 64 + ct * 16 + lr] = f2b_hw(o);
        }
    }
}

// ---------------------------------------------------------------------------
extern "C" void kernel_launch(void* const* d_in, const int* in_sizes, int n_in,
                              void* d_out, int out_size, void* d_ws, size_t ws_size,
                              hipStream_t stream)
{
    (void)in_sizes; (void)n_in; (void)out_size; (void)ws_size;
    const float* x      = (const float*)d_in[0];
    const float* wq_s   = (const float*)d_in[1];
    const float* wk_s   = (const float*)d_in[2];
    const float* wv_r   = (const float*)d_in[3];
    const float* wq_r   = (const float*)d_in[4];
    const float* wk_ret = (const float*)d_in[5];
    const float* w_out  = (const float*)d_in[6];

    char* ws = (char*)d_ws;                            // needs ~24.3 MB
    unsigned short* xb  = (unsigned short*)(ws + 0);          // [4096][512]
    unsigned short* wt  = (unsigned short*)(ws + 4194304);    // [1664][512]
    unsigned short* qsb = (unsigned short*)(ws + 5898240);    // [2][8][2048][64]
    unsigned short* ksb = (unsigned short*)(ws + 10092544);   // [2][8][2048][64]
    unsigned short* rqb = (unsigned short*)(ws + 14286848);   // [2][8][2048][64]
    unsigned short* vtb = (unsigned short*)(ws + 18481152);   // [2][128][2048]
    unsigned short* obb = (unsigned short*)(ws + 19529728);   // [2][2048][512]
    unsigned short* wot = (unsigned short*)(ws + 23724032);   // [512][512]
    unsigned short* wkt = (unsigned short*)(ws + 24248320);   // [64][64]

    hipLaunchKernelGGL(k_elem, dim3(1024), dim3(256), 0, stream,
                       x, wk_ret, xb, wkt);
    hipLaunchKernelGGL(k_trans, dim3(1088), dim3(256), 0, stream,
                       wq_s, wk_s, wv_r, wq_r, w_out, wt, wot);
    hipLaunchKernelGGL((k_gemm<0>), dim3(32, 26), dim3(256), 0, stream,
                       xb, wt, qsb, ksb, rqb, vtb, (float*)nullptr);
    hipLaunchKernelGGL(k_attn, dim3(512), dim3(512), 0, stream,
                       qsb, ksb, rqb, vtb, wkt, obb);
    hipLaunchKernelGGL((k_gemm<1>), dim3(32, 8), dim3(256), 0, stream,
                       obb, wot, (unsigned short*)nullptr, (unsigned short*)nullptr,
                       (unsigned short*)nullptr, (unsigned short*)nullptr, (float*)d_out);
}

// Round 13
// 76.622 us; speedup vs baseline: 1.4942x; 1.2003x over previous
//
#include <hip/hip_runtime.h>
#include <hip/hip_bf16.h>

#define DEV __device__ __forceinline__

typedef __attribute__((ext_vector_type(8))) short bf16x8;
typedef __attribute__((ext_vector_type(4))) float f32x4;

DEV float b2f(unsigned short u) {
    unsigned int v = ((unsigned int)u) << 16;
    float f; __builtin_memcpy(&f, &v, 4); return f;
}
DEV unsigned short f2b(float f) {            // RNE via bit-ops
    unsigned int v; __builtin_memcpy(&v, &f, 4);
    v = (v + 0x7fffu + ((v >> 16) & 1u)) >> 16;
    return (unsigned short)v;
}
DEV unsigned short f2b_hw(float f) {         // hardware cvt (RNE)
    __hip_bfloat16 h = __float2bfloat16(f);
    unsigned short u; __builtin_memcpy(&u, &h, 2); return u;
}
DEV float exp2raw(float x) { return __builtin_amdgcn_exp2f(x); }  // raw v_exp_f32

DEV f32x4 mfma16(bf16x8 a, bf16x8 b, f32x4 c) {
    return __builtin_amdgcn_mfma_f32_16x16x32_bf16(a, b, c, 0, 0, 0);
}

// global -> LDS async copy, 16B per lane; lds dest = uniform base + lane*16
DEV void stage16(const void* g, void* l) {
    __builtin_amdgcn_global_load_lds((const __attribute__((address_space(1))) void*)g,
                                     (__attribute__((address_space(3))) void*)l, 16, 0, 0);
}

#define WAIT_VM6()  asm volatile("s_waitcnt vmcnt(6)" ::: "memory")
#define WAIT_VM3()  asm volatile("s_waitcnt vmcnt(3)" ::: "memory")
#define WAIT_VM0()  asm volatile("s_waitcnt vmcnt(0)" ::: "memory")
#define WAIT_LGKM() asm volatile("s_waitcnt lgkmcnt(0)" ::: "memory")
#define BAR()       __builtin_amdgcn_s_barrier()
#define SCHED()     __builtin_amdgcn_sched_barrier(0)

constexpr float SCALE_L2E = 0.125f * 1.44269504088896340736f;  // DH^-0.5 * log2(e)

// ---------------------------------------------------------------------------
// K0a: elementwise fp32->bf16: xb[4096][512] = x ; wkt[64][64] = wk_ret copy.
// ---------------------------------------------------------------------------
__global__ void k_elem(const float* __restrict__ x,
                       const float* __restrict__ wk_ret,
                       unsigned short* __restrict__ xb,
                       unsigned short* __restrict__ wkt)
{
    const int T1 = 4096 * 512;
    const int T4 = 64 * 64;
    const int total = T1 + T4;
    for (int idx = blockIdx.x * blockDim.x + threadIdx.x; idx < total;
         idx += gridDim.x * blockDim.x) {
        if (idx < T1) xb[idx] = f2b(x[idx]);
        else          wkt[idx - T1] = f2b(wk_ret[idx - T1]);
    }
}

// ---------------------------------------------------------------------------
// K0b: LDS-tiled 32x32 transposes (coalesced read AND write):
//  wt[1664][512]: rows 0..511 = wq_s^T, 512..1023 = wk_s^T,
//                 1024..1151 = wv_r^T, 1152..1663 = wq_r^T
//  wot[512][512] = w_out^T
// ---------------------------------------------------------------------------
__global__ __launch_bounds__(256) void k_trans(const float* __restrict__ wq_s,
                                               const float* __restrict__ wk_s,
                                               const float* __restrict__ wv_r,
                                               const float* __restrict__ wq_r,
                                               const float* __restrict__ w_out,
                                               unsigned short* __restrict__ wt,
                                               unsigned short* __restrict__ wot)
{
    __shared__ float tl[32][33];
    int m = blockIdx.x;
    const float* src; unsigned short* dst;
    int base, srcld, kt, nt;
    if (m < 256)      { src = wq_s;  dst = wt;  base = 0;    srcld = 512; kt = m >> 4; nt = m & 15; }
    else if (m < 512) { m -= 256; src = wk_s;  dst = wt;  base = 512;  srcld = 512; kt = m >> 4; nt = m & 15; }
    else if (m < 576) { m -= 512; src = wv_r;  dst = wt;  base = 1024; srcld = 128; kt = m >> 2; nt = m & 3; }
    else if (m < 832) { m -= 576; src = wq_r;  dst = wt;  base = 1152; srcld = 512; kt = m >> 4; nt = m & 15; }
    else              { m -= 832; src = w_out; dst = wot; base = 0;    srcld = 512; kt = m >> 4; nt = m & 15; }

    const int r = threadIdx.x >> 5, c = threadIdx.x & 31;
#pragma unroll
    for (int s = 0; s < 4; ++s) {
        int rr = r + 8 * s;
        tl[rr][c] = src[(size_t)(kt * 32 + rr) * srcld + nt * 32 + c];
    }
    __syncthreads();
#pragma unroll
    for (int s = 0; s < 4; ++s) {
        int rr = r + 8 * s;
        dst[(size_t)(base + nt * 32 + rr) * 512 + kt * 32 + c] = f2b(tl[c][rr]);
    }
}

// ---------------------------------------------------------------------------
// K1/K3: staged GEMM  C[4096][N*] = A(bf16 [4096][512]) @ Bt(bf16 [N][512])^T
// BM=128, BN=64, BK=64; 4 waves 2x2, wave (wr,wc) owns 64x32 of C.
// Raw s_barrier + counted vmcnt (R10 structure, unchanged).
// EPI=0: scatter epilogue into qs/ks/rqb/vt.  EPI=1: fp32 store epilogue.
// ---------------------------------------------------------------------------
template<int EPI>
__global__ __launch_bounds__(256, 2) void k_gemm(const unsigned short* __restrict__ A,
                                                 const unsigned short* __restrict__ Bt,
                                                 unsigned short* __restrict__ qs,
                                                 unsigned short* __restrict__ ks,
                                                 unsigned short* __restrict__ rqb,
                                                 unsigned short* __restrict__ vt,
                                                 float* __restrict__ out)
{
    __shared__ unsigned char ab_lds[49152];

    const int tid = threadIdx.x;
    const int lane = tid & 63, wid = tid >> 6;
    const int lr = lane & 15, lg = lane >> 4;
    const int wr = wid >> 1, wc = wid & 1;
    const int brow0 = blockIdx.x * 128;
    const int bcol0 = blockIdx.y * 64;

    const int sub = lane >> 3;            // row within 8-row stripe
    const int chk = lane & 7;             // 16B chunk slot
    const int scs = chk ^ sub;            // swizzled source chunk

    const f32x4 z = {0.f, 0.f, 0.f, 0.f};
    f32x4 acc[4][2];
#pragma unroll
    for (int m = 0; m < 4; ++m)
#pragma unroll
        for (int n = 0; n < 2; ++n) acc[m][n] = z;

    const unsigned short* Ab = A + (size_t)brow0 * 512;

    auto STAGE = [&](int buf, int k0) {
        unsigned char* ab = ab_lds + buf * 16384;
        unsigned char* bb = ab_lds + 32768 + buf * 8192;
#pragma unroll
        for (int ii = 0; ii < 4; ++ii) {
            int r0 = wid * 32 + ii * 8;
            const unsigned short* g = Ab + (size_t)(r0 + sub) * 512 + k0 + scs * 8;
            stage16(g, ab + r0 * 128);
        }
#pragma unroll
        for (int ii = 0; ii < 2; ++ii) {
            int r0 = wid * 16 + ii * 8;
            const unsigned short* g = Bt + (size_t)(bcol0 + r0 + sub) * 512 + k0 + scs * 8;
            stage16(g, bb + r0 * 128);
        }
    };

    auto COMPUTE = [&](const int cur) {
        const unsigned char* ab = ab_lds + cur * 16384;
        const unsigned char* bb = ab_lds + 32768 + cur * 8192;
#pragma unroll
        for (int ksb = 0; ksb < 2; ++ksb) {
            const int c = ksb * 4 + lg;                       // k-chunk 0..7
            bf16x8 bfr[2];
#pragma unroll
            for (int n = 0; n < 2; ++n) {
                int row = wc * 32 + n * 16 + lr;
                bfr[n] = *(const bf16x8*)(bb + row * 128 + ((c ^ (row & 7)) << 4));
            }
#pragma unroll
            for (int m = 0; m < 4; ++m) {
                int row = wr * 64 + m * 16 + lr;
                bf16x8 af = *(const bf16x8*)(ab + row * 128 + ((c ^ (row & 7)) << 4));
                acc[m][0] = mfma16(af, bfr[0], acc[m][0]);
                acc[m][1] = mfma16(af, bfr[1], acc[m][1]);
            }
        }
    };

    STAGE(0, 0);
#pragma unroll 1
    for (int it = 0; it < 3; ++it) {
        STAGE(1, (2 * it + 1) * 64);
        WAIT_VM6(); BAR(); SCHED();
        COMPUTE(0);
        WAIT_LGKM(); SCHED(); BAR(); SCHED();
        STAGE(0, (2 * it + 2) * 64);
        WAIT_VM6(); BAR(); SCHED();
        COMPUTE(1);
        WAIT_LGKM(); SCHED(); BAR(); SCHED();
    }
    STAGE(1, 7 * 64);
    WAIT_VM6(); BAR(); SCHED();
    COMPUTE(0);
    WAIT_LGKM(); SCHED(); BAR(); SCHED();
    WAIT_VM0(); BAR(); SCHED();
    COMPUTE(1);

#pragma unroll
    for (int m = 0; m < 4; ++m) {
#pragma unroll
        for (int n = 0; n < 2; ++n) {
#pragma unroll
            for (int i = 0; i < 4; ++i) {
                int gr = brow0 + wr * 64 + m * 16 + lg * 4 + i;
                int gc = bcol0 + wc * 32 + n * 16 + lr;
                float v = acc[m][n][i];
                if (EPI == 1) {
                    out[(size_t)gr * 512 + gc] = v;
                } else {
                    int b = gr >> 11, in = gr & 2047;
                    if (gc < 512) {
                        int s = gc >> 6, d = gc & 63;
                        qs[((b * 8 + s) * 2048 + in) * 64 + d] = f2b(v * SCALE_L2E);
                    } else if (gc < 1024) {
                        int cgc = gc - 512; int s = cgc >> 6, d = cgc & 63;
                        ks[((b * 8 + s) * 2048 + in) * 64 + d] = f2b(v);
                    } else if (gc < 1152) {
                        int cgc = gc - 1024;             // 0..127 = r*64+d
                        vt[(b * 128 + cgc) * 2048 + in] = f2b(v);
                    } else {
                        int cgc = gc - 1152; int s = cgc >> 6, d = cgc & 63;
                        rqb[((b * 8 + s) * 2048 + in) * 64 + d] = f2b(v * SCALE_L2E);
                    }
                }
            }
        }
    }
}

// ---------------------------------------------------------------------------
// K2: flash attention + fused retrieval composition.
// R13: swapped QK^T (S^T = mfma(K,Q)) with PERMUTED K-rows so each lane's
// 8 P-values land exactly at V-natural key slots — P never touches LDS.
//   K A-row m of mfma call a reads LDS K row  h*32 + (m>>2)*8 + a*4 + (m&3).
//   Then lane (lg,lr): s[a][i] = S[qrow=lr][key = h*32 + lg*8 + a*4 + i],
//   so pa[j]=p[j>>2][j&3] covers keys h*32+lg*8+j  == the PV A-fragment.
// Softmax: per-lane scalar m (row lr); rare rescale = 2 shuffles; row-sum
// l = lane-local adds + 2 end shuffles. exp2 = raw v_exp_f32 (log2 units).
// P->bf16 via 4x v_cvt_pk_bf16_f32. PV + acc layout unchanged from R12.
// ---------------------------------------------------------------------------
__global__ __launch_bounds__(512, 4) void k_attn(const unsigned short* __restrict__ qs,
                                                 const unsigned short* __restrict__ ks,
                                                 const unsigned short* __restrict__ rqb,
                                                 const unsigned short* __restrict__ vt,
                                                 const unsigned short* __restrict__ wkt,
                                                 unsigned short* __restrict__ ob)
{
    // 2 bufs x (K 8KB @ +0 | V 16KB @ +8192) = 48KB; merge region aliases
    // this after the main loop (all kv reads done + barrier).
    __shared__ unsigned char kv_lds[49152];

    const int tid = threadIdx.x;
    const int lane = tid & 63, wid = tid >> 6;        // wid 0..7
    const int lr = lane & 15, lg = lane >> 4;
    const int qsub = wid & 3, h = wid >> 2;
    const int bid = blockIdx.x;
    const int bs = bid >> 5, qt = bid & 31;           // bs = b*8+s
    const int gb = bs >> 3, gs = bs & 7;
    const int qrow0 = qt * 64 + qsub * 16;

    const int sub = lane >> 3;                        // row within 8-row stripe
    const int scs = (lane & 7) ^ sub;                 // swizzled source chunk

    // Q fragments (B-operand layout: lane l&15 = qrow), in regs all kernel
    const unsigned short* qbase = qs + ((size_t)bs * 2048 + qrow0 + lr) * 64 + lg * 8;
    const bf16x8 q0 = *(const bf16x8*)(qbase);
    const bf16x8 q1 = *(const bf16x8*)(qbase + 32);

    const unsigned short* kbase = ks + (size_t)bs * 131072;     // [2048][64]
    const unsigned short* vbase = vt + (size_t)gb * 262144;     // [128][2048]

    const f32x4 z = {0.f, 0.f, 0.f, 0.f};

    float m_r = -3.0e38f;                             // running max, row lr
    float acc_l = 0.f;                                // lane-partial row sum
    f32x4 acc[8];                                     // O rows lg*4+i, d c8*16+lr
#pragma unroll
    for (int c8 = 0; c8 < 8; ++c8) acc[c8] = z;

    // --- permuted K-read offsets (hoisted): rk(a) = h*32+(lr>>2)*8+a*4+(lr&3)
    const int rk0 = h * 32 + (lr >> 2) * 8 + (lr & 3);
    const int rk1 = rk0 + 4;
    const int ko0a = rk0 * 128 + ((lg ^ (rk0 & 7)) << 4);
    const int ko0b = rk0 * 128 + (((lg + 4) ^ (rk0 & 7)) << 4);
    const int ko1a = rk1 * 128 + ((lg ^ (rk1 & 7)) << 4);
    const int ko1b = rk1 * 128 + (((lg + 4) ^ (rk1 & 7)) << 4);
    // --- V-read offset: chunk (h*4+lg) ^ (lr&7), d-row (c8*16+lr)
    const int vx = (((h * 4 + lg) ^ (lr & 7)) << 4) + lr * 128;

    // --- stage stripes: 24 x 1KB per tile; wave stages 3w..3w+2
    const unsigned short* sp[3];
    int step[3], loff[3];
#pragma unroll
    for (int j = 0; j < 3; ++j) {
        int s = wid * 3 + j;
        if (s < 8) { sp[j] = kbase + (size_t)(s * 8 + sub) * 64 + scs * 8;          step[j] = 4096; }
        else       { sp[j] = vbase + (size_t)((s - 8) * 8 + sub) * 2048 + scs * 8;  step[j] = 64;   }
        loff[j] = s * 1024;
    }

    auto STAGE = [&](const int buf) {
        unsigned char* base = kv_lds + buf * 24576;
#pragma unroll
        for (int j = 0; j < 3; ++j) {
            stage16(sp[j], base + loff[j]);
            sp[j] += step[j];
        }
    };

    auto COMPUTE = [&](const int cur) {
        const unsigned char* kb = kv_lds + cur * 24576;
        const unsigned char* vb = kb + 8192;

        // --- S^T = K_perm · Q^T  (2 calls x K-dim 64 via 2 mfma each)
        f32x4 s[2];
        __builtin_amdgcn_s_setprio(1);
        {
            bf16x8 kf0 = *(const bf16x8*)(kb + ko0a);
            bf16x8 kf1 = *(const bf16x8*)(kb + ko0b);
            f32x4 t = z;
            t = mfma16(kf0, q0, t);
            t = mfma16(kf1, q1, t);
            s[0] = t;
        }
        {
            bf16x8 kf0 = *(const bf16x8*)(kb + ko1a);
            bf16x8 kf1 = *(const bf16x8*)(kb + ko1b);
            f32x4 t = z;
            t = mfma16(kf0, q0, t);
            t = mfma16(kf1, q1, t);
            s[1] = t;
        }
        __builtin_amdgcn_s_setprio(0);

        // --- deferred-max online softmax (log2 units), row = lr per lane
        float lm = fmaxf(fmaxf(fmaxf(s[0][0], s[0][1]), fmaxf(s[0][2], s[0][3])),
                         fmaxf(fmaxf(s[1][0], s[1][1]), fmaxf(s[1][2], s[1][3])));
        if (__any(lm > m_r + 8.0f)) {
            float mx = fmaxf(lm, __shfl_xor(lm, 16));
            mx = fmaxf(mx, __shfl_xor(mx, 32));
            float m_new = fmaxf(m_r, mx);
            float alpha = exp2raw(m_r - m_new);
            float al[4];
#pragma unroll
            for (int i = 0; i < 4; ++i) al[i] = __shfl(alpha, lg * 4 + i, 16);
#pragma unroll
            for (int c8 = 0; c8 < 8; ++c8)
#pragma unroll
                for (int i = 0; i < 4; ++i) acc[c8][i] *= al[i];
            acc_l *= alpha;
            m_r = m_new;
        }

        // --- P = exp2(S - m); pack to PV A-fragment (keys h*32+lg*8+j)
        float p[8];
#pragma unroll
        for (int a = 0; a < 2; ++a)
#pragma unroll
            for (int i = 0; i < 4; ++i)
                p[a * 4 + i] = exp2raw(s[a][i] - m_r);
        acc_l += ((p[0] + p[1]) + (p[2] + p[3])) + ((p[4] + p[5]) + (p[6] + p[7]));
        unsigned int pu[4];
#pragma unroll
        for (int t2 = 0; t2 < 4; ++t2)
            asm("v_cvt_pk_bf16_f32 %0, %1, %2" : "=v"(pu[t2]) : "v"(p[2 * t2]), "v"(p[2 * t2 + 1]));
        bf16x8 pa;
        __builtin_memcpy(&pa, pu, 16);

        // --- PV: acc[c8] rows = qrows lg*4+i, cols d = c8*16+lr
        __builtin_amdgcn_s_setprio(1);
#pragma unroll
        for (int c8 = 0; c8 < 8; ++c8) {
            bf16x8 vf = *(const bf16x8*)(vb + c8 * 2048 + vx);
            acc[c8] = mfma16(pa, vf, acc[c8]);
        }
        __builtin_amdgcn_s_setprio(0);
    };

    STAGE(0);                                         // tile 0 -> buf0

#pragma unroll 1
    for (int it = 0; it < 15; ++it) {
        STAGE(1);                                     // tile 2it+1
        WAIT_VM3(); BAR(); SCHED();
        COMPUTE(0);                                   // tile 2it
        WAIT_LGKM(); SCHED(); BAR(); SCHED();
        STAGE(0);                                     // tile 2it+2
        WAIT_VM3(); BAR(); SCHED();
        COMPUTE(1);                                   // tile 2it+1
        WAIT_LGKM(); SCHED(); BAR(); SCHED();
    }
    STAGE(1);                                         // tile 31
    WAIT_VM3(); BAR(); SCHED();
    COMPUTE(0);                                       // tile 30
    WAIT_LGKM(); SCHED(); BAR(); SCHED();
    WAIT_VM0(); BAR(); SCHED();
    COMPUTE(1);                                       // tile 31

    // --- reduce row-sum l across the 4 lane-groups holding row lr
    float l2 = acc_l + __shfl_xor(acc_l, 16);
    float l_row = l2 + __shfl_xor(l2, 32);

    // --- merge halves through LDS (aliases dead kv region)
    __syncthreads();
    float* mrg = (float*)kv_lds;                      // [4][16][132] = 33792 B
    float* ml  = (float*)(kv_lds + 33792);            // [4][16][2]   = 512 B
    if (h == 1) {
#pragma unroll
        for (int c8 = 0; c8 < 8; ++c8)
#pragma unroll
            for (int i = 0; i < 4; ++i)
                mrg[(qsub * 16 + lg * 4 + i) * 132 + c8 * 16 + lr] = acc[c8][i];
        if (lane < 16) {
            ml[(qsub * 16 + lane) * 2 + 0] = m_r;     // row lr == lane
            ml[(qsub * 16 + lane) * 2 + 1] = l_row;
        }
    }
    __syncthreads();
    if (h == 1) return;

    // h==0: redistribute own m/l from row-lr layout to acc rows lg*4+i
    float m_own[4], l_own[4];
#pragma unroll
    for (int i = 0; i < 4; ++i) {
        m_own[i] = __shfl(m_r,  lg * 4 + i, 16);
        l_own[i] = __shfl(l_row, lg * 4 + i, 16);
    }

    // flash-merge partner partials
    float inv[4];
    f32x4 accM[8];
#pragma unroll
    for (int i = 0; i < 4; ++i) {
        float m_b = ml[(qsub * 16 + lg * 4 + i) * 2 + 0];
        float l_b = ml[(qsub * 16 + lg * 4 + i) * 2 + 1];
        float m_new = fmaxf(m_own[i], m_b);
        float fa = exp2raw(m_own[i] - m_new);
        float fb = exp2raw(m_b - m_new);
        inv[i] = 1.0f / (l_own[i] * fa + l_b * fb);
#pragma unroll
        for (int c8 = 0; c8 < 8; ++c8)
            accM[c8][i] = acc[c8][i] * fa + mrg[(qsub * 16 + lg * 4 + i) * 132 + c8 * 16 + lr] * fb;
    }

    // rq fragments (pre-scaled by DH^-0.5*log2e in k_gemm<0>)
    const unsigned short* rqbase = rqb + ((size_t)bs * 2048 + qrow0 + lr) * 64 + lg * 8;
    const bf16x8 rq0 = *(const bf16x8*)(rqbase);
    const bf16x8 rq1 = *(const bf16x8*)(rqbase + 32);

    // stage 2 via MFMA: T[q][d] = sum_dp rq[q][dp] * wk_ret[d][dp]
    f32x4 Tt[4];
#pragma unroll
    for (int ct = 0; ct < 4; ++ct) {
        bf16x8 wb0 = *(const bf16x8*)(wkt + (ct * 16 + lr) * 64 + lg * 8);
        bf16x8 wb1 = *(const bf16x8*)(wkt + (ct * 16 + lr) * 64 + 32 + lg * 8);
        f32x4 t = z;
        t = mfma16(rq0, wb0, t);
        t = mfma16(rq1, wb1, t);
        Tt[ct] = t;
    }

    // sim_r[row] = sum_{d} T[row][d] * retrN[row][r*64+d]   (log2 units)
    float w0v[4], w1v[4];
#pragma unroll
    for (int i = 0; i < 4; ++i) {
        float s0 = 0.f, s1 = 0.f;
#pragma unroll
        for (int ct = 0; ct < 4; ++ct) {
            s0 += Tt[ct][i] * accM[ct][i];
            s1 += Tt[ct][i] * accM[4 + ct][i];
        }
        s0 *= inv[i]; s1 *= inv[i];
        s0 += __shfl_xor(s0, 1, 16); s1 += __shfl_xor(s1, 1, 16);
        s0 += __shfl_xor(s0, 2, 16); s1 += __shfl_xor(s1, 2, 16);
        s0 += __shfl_xor(s0, 4, 16); s1 += __shfl_xor(s1, 4, 16);
        s0 += __shfl_xor(s0, 8, 16); s1 += __shfl_xor(s1, 8, 16);
        float mm = fmaxf(s0, s1);
        float e0 = exp2raw(s0 - mm), e1 = exp2raw(s1 - mm);
        float inw = 1.0f / (e0 + e1);
        w0v[i] = e0 * inw; w1v[i] = e1 * inw;
    }

    // --- combine r=2 and store ob[b][n][gs*64 + d]
#pragma unroll
    for (int ct = 0; ct < 4; ++ct) {
#pragma unroll
        for (int i = 0; i < 4; ++i) {
            float o = (w0v[i] * accM[ct][i] + w1v[i] * accM[4 + ct][i]) * inv[i];
            ob[((size_t)gb * 2048 + qrow0 + lg * 4 + i) * 512 + gs * 64 + ct * 16 + lr] = f2b_hw(o);
        }
    }
}

// ---------------------------------------------------------------------------
extern "C" void kernel_launch(void* const* d_in, const int* in_sizes, int n_in,
                              void* d_out, int out_size, void* d_ws, size_t ws_size,
                              hipStream_t stream)
{
    (void)in_sizes; (void)n_in; (void)out_size; (void)ws_size;
    const float* x      = (const float*)d_in[0];
    const float* wq_s   = (const float*)d_in[1];
    const float* wk_s   = (const float*)d_in[2];
    const float* wv_r   = (const float*)d_in[3];
    const float* wq_r   = (const float*)d_in[4];
    const float* wk_ret = (const float*)d_in[5];
    const float* w_out  = (const float*)d_in[6];

    char* ws = (char*)d_ws;                            // needs ~24.3 MB
    unsigned short* xb  = (unsigned short*)(ws + 0);          // [4096][512]
    unsigned short* wt  = (unsigned short*)(ws + 4194304);    // [1664][512]
    unsigned short* qsb = (unsigned short*)(ws + 5898240);    // [2][8][2048][64]
    unsigned short* ksb = (unsigned short*)(ws + 10092544);   // [2][8][2048][64]
    unsigned short* rqb = (unsigned short*)(ws + 14286848);   // [2][8][2048][64]
    unsigned short* vtb = (unsigned short*)(ws + 18481152);   // [2][128][2048]
    unsigned short* obb = (unsigned short*)(ws + 19529728);   // [2][2048][512]
    unsigned short* wot = (unsigned short*)(ws + 23724032);   // [512][512]
    unsigned short* wkt = (unsigned short*)(ws + 24248320);   // [64][64]

    hipLaunchKernelGGL(k_elem, dim3(1024), dim3(256), 0, stream,
                       x, wk_ret, xb, wkt);
    hipLaunchKernelGGL(k_trans, dim3(1088), dim3(256), 0, stream,
                       wq_s, wk_s, wv_r, wq_r, w_out, wt, wot);
    hipLaunchKernelGGL((k_gemm<0>), dim3(32, 26), dim3(256), 0, stream,
                       xb, wt, qsb, ksb, rqb, vtb, (float*)nullptr);
    hipLaunchKernelGGL(k_attn, dim3(512), dim3(512), 0, stream,
                       qsb, ksb, rqb, vtb, wkt, obb);
    hipLaunchKernelGGL((k_gemm<1>), dim3(32, 8), dim3(256), 0, stream,
                       obb, wot, (unsigned short*)nullptr, (unsigned short*)nullptr,
                       (unsigned short*)nullptr, (unsigned short*)nullptr, (float*)d_out);
}